// Round 11
// baseline (232.963 us; speedup 1.0000x reference)
//
#include <hip/hip_runtime.h>
#include <hip/hip_bf16.h>
#include <math.h>

#define GK 75264      // per-frame feature dim (64*1176)
#define NF 256        // frames
#define KC 60         // clusters
#define NSEL 30       // selected spatial centroids
#define NCH 196       // gram split-K channels (K=384 each, 12 steps of 32)
#define KM_IT 10

typedef __attribute__((ext_vector_type(8))) short bf16x8;
typedef __attribute__((ext_vector_type(4))) float f32x4;
typedef __attribute__((ext_vector_type(8))) unsigned short u16x8;

__device__ __forceinline__ float b2f(unsigned short u) {
  union { unsigned u32; float f; } c; c.u32 = ((unsigned)u) << 16; return c.f;
}

// ---------------- Stage A: temporal 2x2 pooling -> bf16 split (H, M) --------
__global__ void pool_kernel(const float* __restrict__ x,
                            __hip_bfloat16* __restrict__ H,
                            __hip_bfloat16* __restrict__ M) {
  unsigned id = blockIdx.x * 256u + threadIdx.x;   // exactly 19,267,584 threads
  unsigned m = id / 1176u, o = id - m * 1176u;
  unsigned t = m >> 6, r = m & 63u;
  unsigned ih = r >> 4, iw = (r >> 2) & 3u, s = r & 3u;
  unsigned i8 = ih * 2u + (s >> 1), j8 = iw * 2u + (s & 1u);
  unsigned c = o / 392u, o2 = o - c * 392u;
  unsigned d = o2 / 196u, o3 = o2 - d * 196u;
  unsigned e = o3 / 14u, f = o3 - e * 14u;
  unsigned a = (e >= 7u) ? 1u : 0u, b = (f >= 7u) ? 1u : 0u;
  unsigned ee = 2u * e - 14u * a, ff = 2u * f - 14u * b;
  unsigned xrow = ((t * 8u + i8) * 8u + j8) * 4u + a * 2u + b;
  unsigned xcol = ((c * 2u + d) * 14u + ee) * 14u + ff;
  const float* base = x + (size_t)xrow * 1176u + xcol;
  float v = 0.25f * ((base[0] + base[1]) + (base[14] + base[15]));
  __hip_bfloat16 hb = __float2bfloat16(v);
  float hf = __bfloat162float(hb);
  __hip_bfloat16 mb = __float2bfloat16(v - hf);
  H[id] = hb;
  M[id] = mb;
}

// ---------------- Stage B1: Gram via bf16 MFMA, 3-product split-float -------
// G = H.H^T + H.M^T + M.H^T  (exact to ~2^-18 relative; mm term negligible).
__global__ __launch_bounds__(512) void gram_mfma(const unsigned short* __restrict__ HB,
                                                 const unsigned short* __restrict__ MB,
                                                 float* __restrict__ gpart) {
  __shared__ __align__(16) char sH[256 * 64];
  __shared__ __align__(16) char sM[256 * 64];
  const int ch = blockIdx.x;
  const int t = threadIdx.x;
  const int w = t >> 6, l = t & 63;
  const int rs = w >> 1, cs = w & 1;            // row-strip 0..3, col-strip 0..1
  const int lg = l >> 4, lr = l & 15;

  f32x4 acc[4][8];
#pragma unroll
  for (int i = 0; i < 4; ++i)
#pragma unroll
    for (int j = 0; j < 8; ++j) acc[i][j] = (f32x4){0.f, 0.f, 0.f, 0.f};

  for (int step = 0; step < 12; ++step) {
    const int k0 = ch * 384 + step * 32;
#pragma unroll
    for (int cc = 0; cc < 2; ++cc) {
      int c = t + cc * 512;                     // chunk id in [0,1024)
      int row = c >> 2, kc = c & 3;             // 4x16B chunks per row
      size_t goff = (size_t)row * GK + k0 + kc * 8;
      u16x8 vh = *(const u16x8*)(HB + goff);
      u16x8 vm = *(const u16x8*)(MB + goff);
      int lo = row * 64 + ((kc * 16) ^ (((row >> 1) & 3) << 4));
      *(u16x8*)(sH + lo) = vh;
      *(u16x8*)(sM + lo) = vm;
    }
    __syncthreads();

    bf16x8 Ah[4], Am[4];
#pragma unroll
    for (int tr = 0; tr < 4; ++tr) {
      int row = rs * 64 + tr * 16 + lr;
      int off = row * 64 + ((lg * 16) ^ (((row >> 1) & 3) << 4));
      Ah[tr] = *(const bf16x8*)(sH + off);
      Am[tr] = *(const bf16x8*)(sM + off);
    }
#pragma unroll
    for (int tc = 0; tc < 8; ++tc) {
      int col = cs * 128 + tc * 16 + lr;
      int boff = col * 64 + ((lg * 16) ^ (((col >> 1) & 3) << 4));
      bf16x8 Bh = *(const bf16x8*)(sH + boff);
      bf16x8 Bm = *(const bf16x8*)(sM + boff);
#pragma unroll
      for (int tr = 0; tr < 4; ++tr) {
        acc[tr][tc] = __builtin_amdgcn_mfma_f32_16x16x32_bf16(Ah[tr], Bh, acc[tr][tc], 0, 0, 0);
        acc[tr][tc] = __builtin_amdgcn_mfma_f32_16x16x32_bf16(Ah[tr], Bm, acc[tr][tc], 0, 0, 0);
        acc[tr][tc] = __builtin_amdgcn_mfma_f32_16x16x32_bf16(Am[tr], Bh, acc[tr][tc], 0, 0, 0);
      }
    }
    __syncthreads();
  }

  float* outp = gpart + (size_t)ch * 65536;
#pragma unroll
  for (int tr = 0; tr < 4; ++tr)
#pragma unroll
    for (int tc = 0; tc < 8; ++tc) {
#pragma unroll
      for (int r = 0; r < 4; ++r) {
        int grow = rs * 64 + tr * 16 + lg * 4 + r;   // C/D: row=(lane>>4)*4+reg
        int gcol = cs * 128 + tc * 16 + lr;          // C/D: col=lane&15
        outp[grow * 256 + gcol] = acc[tr][tc][r];
      }
    }
}

__global__ void reduceG(const float* __restrict__ gpart, double* __restrict__ G) {
  int i = blockIdx.x, j = threadIdx.x;
  double s = 0.0;
  for (int c = 0; c < NCH; ++c) s += (double)gpart[(size_t)c * 65536 + i * 256 + j];
  G[i * 256 + j] = s;
}

// ---------------- Stage B2+C+D fused: k-means + ordering + selection --------
// 1024 threads = 16 waves, 2 barriers/iteration, no wave-serial hotspots.
// Numerics: all decision inputs are consistent fp64; summation ORDER is now
// a fixed (deterministic) parallel order rather than the serial-ascending
// one. Rationale: the reference runs this k-means in f32 and our fp64
// pipeline matches its discrete trajectory — so the trajectory tolerates
// ~1e-6 relative perturbation; a consistent fp64 reorder perturbs ~1e-15.
// (r3's failure was an INCONSISTENT fp32/fp64 mix at ~1e-3, a different
// mechanism.) Determinism (bitwise replay) is preserved: fixed tree orders,
// single writer per state word, every cross-wave edge barrier-separated.
//   A-phase (all threads): full 60-cluster argmin (strict <, ascending j),
//     then DISTRIBUTED ballots: wave wid=4a+b owns (cluster j≡a mod 4,
//     word b) -> 15 ballots/wave, unique (j,word) writer.
//   B-phase (wave-task j%16==wid): popcount/dirty/commit, r7's batched
//     column fold for the S row, Q via predicate-masked lane contributions
//     + 6-step shfl_xor tree (fixed order).
__global__ __launch_bounds__(1024) void kmeans_all(
    const double* __restrict__ G,
    int* __restrict__ orderws, int* __restrict__ idxws,
    int* __restrict__ mcount, int* __restrict__ mlist, int* __restrict__ Nout,
    float* __restrict__ out_idx, float* __restrict__ out_ts, float* __restrict__ out_w) {
  __shared__ double S[KC][256];                  // 120 KB member sums (gram space)
  __shared__ double giiL[256];
  __shared__ __align__(16) double qi[KC][2];     // [0]=qnn=Q/n^2, [1]=invn
  __shared__ int Ns[KC];
  __shared__ unsigned long long membw[KC][4];    // committed (last-live) membership
  __shared__ unsigned long long membwN[KC][4];   // this-iteration ballots
  __shared__ int counts64[64], tsum64[64];
  __shared__ float times[KC], wts[KC];
  __shared__ int ord[KC], ord2[KC], sel[NSEL];

  const int tid = threadIdx.x;
  const int i = tid & 255;                       // point / column id
  const int z = tid >> 8;                        // replica group 0..3
  const int lane = tid & 63;
  const int wid = tid >> 6;                      // wave id 0..15
  const int wb = wid & 3;                        // ballot word index (point segment)
  const int wa = wid >> 2;                       // cluster residue class (mod 4)

  // ---- init: centroids = rows round(linspace(0,255,60)) ----
  if (tid < KC) {
    int pj = (int)rint((double)tid * 255.0 / 59.0);
    double q = G[(size_t)pj * 257];
    qi[tid][0] = q; qi[tid][1] = 1.0;            // Q=gii(pj), n=1
    Ns[tid] = 1;
  }
  if (tid < 256) giiL[tid] = G[(size_t)tid * 257];
  for (int j = wid; j < KC; j += 16) {           // wave-task centroid-row copies
    int pj = (int)rint((double)j * 255.0 / 59.0);
    const double* row = G + (size_t)pj * 256 + lane;
    double c0 = row[0], c1 = row[64], c2 = row[128], c3 = row[192];
    S[j][lane] = c0; S[j][64 + lane] = c1; S[j][128 + lane] = c2; S[j][192 + lane] = c3;
  }
  // distributed init ballots: wave (4a+b) -> clusters j=a+4t, word b
#pragma unroll
  for (int t = 0; t < 15; ++t) {
    int j = wa + 4 * t;
    int pj = (int)rint((double)j * 255.0 / 59.0);
    unsigned long long mm = __ballot(i == pj);
    if (lane == 0) membw[j][wb] = mm;
  }
  __syncthreads();

  const double gii = giiL[i];

  for (int it = 0; it < KM_IT; ++it) {
    // ---- A: full 60-cluster argmin (all threads; strict <, ascending j) ----
    double bd = 1e300; int bb = 0;
    for (int j = 0; j < KC; ++j) {
      double2 qv = *(const double2*)&qi[j][0];
      double dd = gii + qv.x - 2.0 * S[j][i] * qv.y;
      if (dd < bd) { bd = dd; bb = j; }
    }
    // distributed ballots: this wave covers point segment wb; it produces
    // word wb for the 15 clusters j === wa (mod 4). Unique (j,word) writer.
#pragma unroll
    for (int t = 0; t < 15; ++t) {
      int j = wa + 4 * t;
      unsigned long long mm = __ballot(bb == j);
      if (lane == 0) membwN[j][wb] = mm;
    }
    __syncthreads();                             // B1

    // ---- B: wave-task per-cluster commit + S fold + Q tree ----
    for (int j = wid; j < KC; j += 16) {
      unsigned long long mw0 = membwN[j][0], mw1 = membwN[j][1];
      unsigned long long mw2 = membwN[j][2], mw3 = membwN[j][3];
      int c = __builtin_popcountll(mw0) + __builtin_popcountll(mw1)
            + __builtin_popcountll(mw2) + __builtin_popcountll(mw3);
      if (c == 0) continue;                      // frozen: keep state
      int d = (mw0 != membw[j][0]) | (mw1 != membw[j][1])
            | (mw2 != membw[j][2]) | (mw3 != membw[j][3]);
      if (!d) continue;                          // unchanged: same bits, skip
      if (lane == 0) {
        membw[j][0] = mw0; membw[j][1] = mw1; membw[j][2] = mw2; membw[j][3] = mw3;
      }
      // S row fold: lane covers columns {lane, +64, +128, +192};
      // members in 4-wide batched rounds (deterministic fixed order).
      double a0 = 0.0, a1 = 0.0, a2 = 0.0, a3 = 0.0;
#pragma unroll
      for (int w = 0; w < 4; ++w) {
        unsigned long long mm = membwN[j][w];     // wave-uniform
        const double* gb = G + (size_t)w * 64 * 256;
        while (mm) {
          int bs[4];
#pragma unroll
          for (int k = 0; k < 4; ++k) {
            if (mm) { bs[k] = __builtin_ctzll(mm); mm &= mm - 1; } else bs[k] = -1;
          }
          double g0[4], g1[4], g2[4], g3[4];
#pragma unroll
          for (int k = 0; k < 4; ++k) {
            if (bs[k] >= 0) {
              const double* row = gb + (size_t)bs[k] * 256 + lane;
              g0[k] = row[0]; g1[k] = row[64]; g2[k] = row[128]; g3[k] = row[192];
            } else { g0[k] = 0.0; g1[k] = 0.0; g2[k] = 0.0; g3[k] = 0.0; }
          }
#pragma unroll
          for (int k = 0; k < 4; ++k) {
            a0 += g0[k]; a1 += g1[k]; a2 += g2[k]; a3 += g3[k];
          }
        }
      }
      S[j][lane] = a0; S[j][64 + lane] = a1; S[j][128 + lane] = a2; S[j][192 + lane] = a3;

      // Q = sum of S[j][p] over members p: predicate-masked lane
      // contributions + fixed 6-step shfl_xor tree (deterministic).
      double ql = 0.0;
      ql += ((mw0 >> lane) & 1ULL) ? a0 : 0.0;
      ql += ((mw1 >> lane) & 1ULL) ? a1 : 0.0;
      ql += ((mw2 >> lane) & 1ULL) ? a2 : 0.0;
      ql += ((mw3 >> lane) & 1ULL) ? a3 : 0.0;
#pragma unroll
      for (int o = 32; o > 0; o >>= 1) ql += __shfl_xor(ql, o, 64);
      if (lane == 0) {
        double n = (double)c;
        Ns[j] = c;
        qi[j][1] = 1.0 / n;
        qi[j][0] = ql / (n * n);
      }
    }
    __syncthreads();                             // B2
  }

  // ---- final assignment + ordering (group 0 computes; full argmin) ----
  if (tid < 64) { counts64[tid] = 0; tsum64[tid] = 0; }
  __syncthreads();
  if (z == 0) {
    double bd = 1e300; int bb = 0;
    for (int j = 0; j < KC; ++j) {
      double2 qv = *(const double2*)&qi[j][0];
      double dd = gii + qv.x - 2.0 * S[j][i] * qv.y;
      if (dd < bd) { bd = dd; bb = j; }
    }
    atomicAdd(&counts64[bb], 1);
    atomicAdd(&tsum64[bb], i);
  }
  __syncthreads();
  if (tid < KC) times[tid] = (float)tsum64[tid] / fmaxf((float)counts64[tid], 1.0f);
  __syncthreads();
  if (tid < KC) {                                // stable argsort(times)
    float ti = times[tid]; int r = 0;
    for (int s = 0; s < KC; ++s) {
      float ts = times[s];
      r += (ts < ti) || (ts == ti && s < tid);
    }
    ord[r] = tid;
  }
  __syncthreads();
  if (tid < KC) wts[tid] = (float)counts64[ord[tid]];
  __syncthreads();
  if (tid < KC) {                                // stable argsort(-wts)
    float wi = wts[tid]; int r = 0;
    for (int s = 0; s < KC; ++s) {
      float wsv = wts[s];
      r += (wsv > wi) || (wsv == wi && s < tid);
    }
    ord2[r] = tid;
  }
  __syncthreads();
  if (tid < KC) {
    int j = ord[tid];
    orderws[tid] = j;
    out_w[tid] = (float)counts64[j];
    out_ts[tid] = rintf(times[j]);
    Nout[tid] = Ns[tid];
  }
  if (tid < NSEL) sel[tid] = ord[ord2[tid]];
  if (tid < KC) {                                // member lists (last-live membership)
    int c = 0;
#pragma unroll
    for (int w = 0; w < 4; ++w) {
      unsigned long long mm = membw[tid][w];
      while (mm) {
        int b = __builtin_ctzll(mm);
        mlist[tid * 256 + (c++)] = w * 64 + b;
        mm &= mm - 1;
      }
    }
    mcount[tid] = c;
  }
  __syncthreads();

  // ---- distidx: 30 argmins; wave w handles sels {w, w+16} ----
  {
    for (int s = wid; s < NSEL; s += 16) {
      int j = sel[s];
      double qn = qi[j][0], iv = qi[j][1];
      unsigned long long key = ~0ULL;
#pragma unroll
      for (int q = 0; q < 4; ++q) {
        int p = lane + 64 * q;
        double v = giiL[p] + qn - 2.0 * S[j][p] * iv;
        float dd = sqrtf(fmaxf((float)v, 0.0f));
        unsigned long long k = (((unsigned long long)__float_as_uint(dd)) << 32) | (unsigned)p;
        if (k < key) key = k;
      }
#pragma unroll
      for (int o = 32; o > 0; o >>= 1) {
        unsigned long long other = __shfl_xor(key, o, 64);
        if (other < key) key = other;
      }
      if (lane == 0) { int bi = (int)(key & 0xffffffffULL); idxws[s] = bi; out_idx[s] = (float)bi; }
    }
  }
}

// ---------------- Stage E fused: gather_spa + write_tem ---------------------
__global__ void tail_kernel(const float* __restrict__ x, const int* __restrict__ idxws,
                            const __hip_bfloat16* __restrict__ HB,
                            const __hip_bfloat16* __restrict__ MB,
                            const int* __restrict__ orderws,
                            const int* __restrict__ mcount, const int* __restrict__ mlist,
                            const int* __restrict__ N,
                            float* __restrict__ out_cat, float* __restrict__ out_tem) {
  int bid = blockIdx.x;
  if (bid < 8820) {
    int pos = bid * 256 + threadIdx.x;           // 30*75264 float4s
    int s = pos / 75264;
    int o = pos - s * 75264;
    ((float4*)out_cat)[pos] = ((const float4*)x)[(size_t)idxws[s] * 75264 + o];
  } else {
    int b2 = bid - 8820;
    int r = b2 / 37, g = b2 - r * 37;
    int col8 = g * 256 + threadIdx.x;            // 9408 groups of 8 elements
    if (col8 >= 9408) return;
    int j = orderws[r];
    int cntm = mcount[j];
    float n = (float)N[j];
    float acc[8];
#pragma unroll
    for (int k = 0; k < 8; ++k) acc[k] = 0.f;
    for (int m = 0; m < cntm; ++m) {
      int p = mlist[j * 256 + m];
      u16x8 hv = *(const u16x8*)((const unsigned short*)HB + (size_t)p * GK + (size_t)col8 * 8);
      u16x8 mv = *(const u16x8*)((const unsigned short*)MB + (size_t)p * GK + (size_t)col8 * 8);
#pragma unroll
      for (int k = 0; k < 8; ++k) acc[k] += b2f(hv[k]) + b2f(mv[k]);
    }
    float4 o0 = make_float4(acc[0] / n, acc[1] / n, acc[2] / n, acc[3] / n);
    float4 o1 = make_float4(acc[4] / n, acc[5] / n, acc[6] / n, acc[7] / n);
    float4* dst = (float4*)out_tem + (size_t)r * 18816 + (size_t)col8 * 2;
    dst[0] = o0;
    dst[1] = o1;
  }
}

extern "C" void kernel_launch(void* const* d_in, const int* in_sizes, int n_in,
                              void* d_out, int out_size, void* d_ws, size_t ws_size,
                              hipStream_t stream) {
  const float* x = (const float*)d_in[0];
  char* ws = (char*)d_ws;
  size_t off = 0;
  __hip_bfloat16* HB = (__hip_bfloat16*)(ws + off); off += (size_t)19267584 * 2;  // 38.5 MB
  __hip_bfloat16* MB = (__hip_bfloat16*)(ws + off); off += (size_t)19267584 * 2;  // 38.5 MB
  double* G    = (double*)(ws + off);    off += (size_t)65536 * 8;
  int* orderws = (int*)(ws + off);       off += 256;
  int* idxws   = (int*)(ws + off);       off += 256;
  int* mcount  = (int*)(ws + off);       off += 256;
  int* Nws     = (int*)(ws + off);       off += 256;
  int* mlist   = (int*)(ws + off);       off += (size_t)KC * 256 * 4;

  float* out = (float*)d_out;
  float* gpart = out;  // NCH*256KB = 51.4 MB scratch inside cat_x region; overwritten later

  const size_t o_cat = 0;
  const size_t o_tem = 9031680;
  const size_t o_idx = 13547520;
  const size_t o_ts  = o_idx + 30;
  const size_t o_w   = o_ts + 60;

  pool_kernel<<<75264, 256, 0, stream>>>(x, HB, MB);
  gram_mfma<<<NCH, 512, 0, stream>>>((const unsigned short*)HB, (const unsigned short*)MB, gpart);
  reduceG<<<256, 256, 0, stream>>>(gpart, G);
  kmeans_all<<<1, 1024, 0, stream>>>(G, orderws, idxws, mcount, mlist, Nws,
                                     out + o_idx, out + o_ts, out + o_w);
  tail_kernel<<<8820 + KC * 37, 256, 0, stream>>>(x, idxws, HB, MB, orderws, mcount, mlist,
                                                  Nws, out + o_cat, out + o_tem);
}

// Round 12
// 215.027 us; speedup vs baseline: 1.0834x; 1.0834x over previous
//
#include <hip/hip_runtime.h>
#include <hip/hip_bf16.h>
#include <math.h>

#define GK 75264      // per-frame feature dim (64*1176)
#define NF 256        // frames
#define KC 60         // clusters
#define NSEL 30       // selected spatial centroids
#define NCH 196       // gram split-K channels (K=384 each, 12 steps of 32)
#define KM_IT 10

typedef __attribute__((ext_vector_type(8))) short bf16x8;
typedef __attribute__((ext_vector_type(4))) float f32x4;
typedef __attribute__((ext_vector_type(8))) unsigned short u16x8;

__device__ __forceinline__ float b2f(unsigned short u) {
  union { unsigned u32; float f; } c; c.u32 = ((unsigned)u) << 16; return c.f;
}

// ---------------- Stage A: temporal 2x2 pooling -> bf16 split (H, M) --------
__global__ void pool_kernel(const float* __restrict__ x,
                            __hip_bfloat16* __restrict__ H,
                            __hip_bfloat16* __restrict__ M) {
  unsigned id = blockIdx.x * 256u + threadIdx.x;   // exactly 19,267,584 threads
  unsigned m = id / 1176u, o = id - m * 1176u;
  unsigned t = m >> 6, r = m & 63u;
  unsigned ih = r >> 4, iw = (r >> 2) & 3u, s = r & 3u;
  unsigned i8 = ih * 2u + (s >> 1), j8 = iw * 2u + (s & 1u);
  unsigned c = o / 392u, o2 = o - c * 392u;
  unsigned d = o2 / 196u, o3 = o2 - d * 196u;
  unsigned e = o3 / 14u, f = o3 - e * 14u;
  unsigned a = (e >= 7u) ? 1u : 0u, b = (f >= 7u) ? 1u : 0u;
  unsigned ee = 2u * e - 14u * a, ff = 2u * f - 14u * b;
  unsigned xrow = ((t * 8u + i8) * 8u + j8) * 4u + a * 2u + b;
  unsigned xcol = ((c * 2u + d) * 14u + ee) * 14u + ff;
  const float* base = x + (size_t)xrow * 1176u + xcol;
  float v = 0.25f * ((base[0] + base[1]) + (base[14] + base[15]));
  __hip_bfloat16 hb = __float2bfloat16(v);
  float hf = __bfloat162float(hb);
  __hip_bfloat16 mb = __float2bfloat16(v - hf);
  H[id] = hb;
  M[id] = mb;
}

// ---------------- Stage B1: Gram via bf16 MFMA, 3-product split-float -------
// G = H.H^T + H.M^T + M.H^T  (exact to ~2^-18 relative; mm term negligible).
__global__ __launch_bounds__(512) void gram_mfma(const unsigned short* __restrict__ HB,
                                                 const unsigned short* __restrict__ MB,
                                                 float* __restrict__ gpart) {
  __shared__ __align__(16) char sH[256 * 64];
  __shared__ __align__(16) char sM[256 * 64];
  const int ch = blockIdx.x;
  const int t = threadIdx.x;
  const int w = t >> 6, l = t & 63;
  const int rs = w >> 1, cs = w & 1;            // row-strip 0..3, col-strip 0..1
  const int lg = l >> 4, lr = l & 15;

  f32x4 acc[4][8];
#pragma unroll
  for (int i = 0; i < 4; ++i)
#pragma unroll
    for (int j = 0; j < 8; ++j) acc[i][j] = (f32x4){0.f, 0.f, 0.f, 0.f};

  for (int step = 0; step < 12; ++step) {
    const int k0 = ch * 384 + step * 32;
#pragma unroll
    for (int cc = 0; cc < 2; ++cc) {
      int c = t + cc * 512;                     // chunk id in [0,1024)
      int row = c >> 2, kc = c & 3;             // 4x16B chunks per row
      size_t goff = (size_t)row * GK + k0 + kc * 8;
      u16x8 vh = *(const u16x8*)(HB + goff);
      u16x8 vm = *(const u16x8*)(MB + goff);
      int lo = row * 64 + ((kc * 16) ^ (((row >> 1) & 3) << 4));
      *(u16x8*)(sH + lo) = vh;
      *(u16x8*)(sM + lo) = vm;
    }
    __syncthreads();

    bf16x8 Ah[4], Am[4];
#pragma unroll
    for (int tr = 0; tr < 4; ++tr) {
      int row = rs * 64 + tr * 16 + lr;
      int off = row * 64 + ((lg * 16) ^ (((row >> 1) & 3) << 4));
      Ah[tr] = *(const bf16x8*)(sH + off);
      Am[tr] = *(const bf16x8*)(sM + off);
    }
#pragma unroll
    for (int tc = 0; tc < 8; ++tc) {
      int col = cs * 128 + tc * 16 + lr;
      int boff = col * 64 + ((lg * 16) ^ (((col >> 1) & 3) << 4));
      bf16x8 Bh = *(const bf16x8*)(sH + boff);
      bf16x8 Bm = *(const bf16x8*)(sM + boff);
#pragma unroll
      for (int tr = 0; tr < 4; ++tr) {
        acc[tr][tc] = __builtin_amdgcn_mfma_f32_16x16x32_bf16(Ah[tr], Bh, acc[tr][tc], 0, 0, 0);
        acc[tr][tc] = __builtin_amdgcn_mfma_f32_16x16x32_bf16(Ah[tr], Bm, acc[tr][tc], 0, 0, 0);
        acc[tr][tc] = __builtin_amdgcn_mfma_f32_16x16x32_bf16(Am[tr], Bh, acc[tr][tc], 0, 0, 0);
      }
    }
    __syncthreads();
  }

  float* outp = gpart + (size_t)ch * 65536;
#pragma unroll
  for (int tr = 0; tr < 4; ++tr)
#pragma unroll
    for (int tc = 0; tc < 8; ++tc) {
#pragma unroll
      for (int r = 0; r < 4; ++r) {
        int grow = rs * 64 + tr * 16 + lg * 4 + r;   // C/D: row=(lane>>4)*4+reg
        int gcol = cs * 128 + tc * 16 + lr;          // C/D: col=lane&15
        outp[grow * 256 + gcol] = acc[tr][tc][r];
      }
    }
}

__global__ void reduceG(const float* __restrict__ gpart, double* __restrict__ G) {
  int i = blockIdx.x, j = threadIdx.x;
  double s = 0.0;
  for (int c = 0; c < NCH; ++c) s += (double)gpart[(size_t)c * 65536 + i * 256 + j];
  G[i * 256 + j] = s;
}

// ---------------- Stage B2+C+D fused: k-means + ordering + selection --------
// 1024 threads = 16 waves. Best-measured configuration (round 7, 216.3 µs):
// 5 barriers/iter; 4x15 P1 split + exact ascending merge; group-0 P2 ballots;
// popcount counts; wave-task P3 (max 4 serial clusters/wave, lane covers 4
// columns); tid<KC P4 Q-fold. All fp64 folds in the validated serial
// ascending orders -> bit-identical trajectory, deterministic replay.
// NOTE (plateau record): seven structural variants (incremental-LDS 224 µs,
// group-recompute 155, THIS 138, grid-split 139+gaps, L2-warm null,
// 3-barrier 145, 2-barrier 155) pin the kmeans floor at ~138 µs — the
// serial dependency depth of 10 iterations on one CU, not any single
// mechanism (spill/latency/barrier/atomic theories each tested, <=20 µs).
__global__ __launch_bounds__(1024) void kmeans_all(
    const double* __restrict__ G,
    int* __restrict__ orderws, int* __restrict__ idxws,
    int* __restrict__ mcount, int* __restrict__ mlist, int* __restrict__ Nout,
    float* __restrict__ out_idx, float* __restrict__ out_ts, float* __restrict__ out_w) {
  __shared__ double S[KC][256];                  // 120 KB member sums (gram space)
  __shared__ double giiL[256];
  __shared__ double pminD[4][256];
  __shared__ int    pminJ[4][256];
  __shared__ __align__(16) double qi[KC][2];     // [0]=qnn=Q/n^2, [1]=invn
  __shared__ int Ns[KC], cnt[KC], dirty[KC];
  __shared__ unsigned long long membw[KC][4];    // committed (last-live) membership
  __shared__ unsigned long long membwN[KC][4];   // this-iteration ballots
  __shared__ int counts64[64], tsum64[64];
  __shared__ float times[KC], wts[KC];
  __shared__ int ord[KC], ord2[KC], sel[NSEL];

  const int tid = threadIdx.x;
  const int i = tid & 255;                       // point / column id
  const int z = tid >> 8;                        // group 0..3 (clusters 15z..15z+14)
  const int lane = tid & 63;
  const int wv4 = (tid >> 6) & 3;                // wave-in-group (64-point segment)
  const int wid = tid >> 6;                      // wave id 0..15

  // ---- init: centroids = rows round(linspace(0,255,60)) ----
  if (tid < KC) {
    int pj = (int)rint((double)tid * 255.0 / 59.0);
    double q = G[(size_t)pj * 257];
    qi[tid][0] = q; qi[tid][1] = 1.0;            // Q=gii(pj), n=1
    Ns[tid] = 1; cnt[tid] = 0; dirty[tid] = 0;
  }
  if (tid < 256) giiL[tid] = G[(size_t)tid * 257];
  for (int j = wid; j < KC; j += 16) {           // wave-task centroid-row copies
    int pj = (int)rint((double)j * 255.0 / 59.0);
    const double* row = G + (size_t)pj * 256 + lane;
    double c0 = row[0], c1 = row[64], c2 = row[128], c3 = row[192];
    S[j][lane] = c0; S[j][64 + lane] = c1; S[j][128 + lane] = c2; S[j][192 + lane] = c3;
  }
  if (z == 0) {
    for (int j = 0; j < KC; ++j) {
      int pj = (int)rint((double)j * 255.0 / 59.0);
      unsigned long long mm = __ballot(i == pj);
      if (lane == 0) membw[j][wv4] = mm;
    }
  }
  __syncthreads();

  const double gii = giiL[i];

  for (int it = 0; it < KM_IT; ++it) {
    // ---- P1: partial argmin over this group's 15 clusters ----
    {
      double bd = 1e300; int bj = 0;
#pragma unroll
      for (int t = 0; t < 15; ++t) {
        int j = z * 15 + t;
        double2 qv = *(const double2*)&qi[j][0];
        double dd = gii + qv.x - 2.0 * S[j][i] * qv.y;
        if (dd < bd) { bd = dd; bj = j; }
      }
      pminD[z][i] = bd; pminJ[z][i] = bj;
    }
    __syncthreads();                             // B1

    // ---- P2: exact first-min merge (ascending g), ballots only ----
    if (z == 0) {
      double bd = pminD[0][i]; int bb = pminJ[0][i];
#pragma unroll
      for (int g = 1; g < 4; ++g) {
        double d2 = pminD[g][i];
        if (d2 < bd) { bd = d2; bb = pminJ[g][i]; }
      }
      for (int j = 0; j < KC; ++j) {
        unsigned long long mm = __ballot(bb == j);
        if (lane == 0) membwN[j][wv4] = mm;
      }
    }
    __syncthreads();                             // B2

    // ---- P2b: counts via popcount; dirty detection; membership commit ----
    if (tid < KC) {
      int c = 0;
#pragma unroll
      for (int w = 0; w < 4; ++w) c += __builtin_popcountll(membwN[tid][w]);
      cnt[tid] = c;
      int d = 0;
      if (c > 0) {
#pragma unroll
        for (int w = 0; w < 4; ++w) d |= (membwN[tid][w] != membw[tid][w]);
        if (d) {
#pragma unroll
          for (int w = 0; w < 4; ++w) membw[tid][w] = membwN[tid][w];
        }
      }
      dirty[tid] = d;
    }
    __syncthreads();                             // B3

    // ---- P3: wave-task recompute of dirty S rows (fp64, ascending order
    //      per column identical to round-4; lane covers 4 columns) ----
    for (int j = wid; j < KC; j += 16) {
      if (!dirty[j]) continue;
      double a0 = 0.0, a1 = 0.0, a2 = 0.0, a3 = 0.0;
#pragma unroll
      for (int w = 0; w < 4; ++w) {
        unsigned long long mm = membwN[j][w];     // wave-uniform
        const double* gb = G + (size_t)w * 64 * 256;
        while (mm) {
          int bs[4];
#pragma unroll
          for (int k = 0; k < 4; ++k) {
            if (mm) { bs[k] = __builtin_ctzll(mm); mm &= mm - 1; } else bs[k] = -1;
          }
          double g0[4], g1[4], g2[4], g3[4];
#pragma unroll
          for (int k = 0; k < 4; ++k) {
            if (bs[k] >= 0) {
              const double* row = gb + (size_t)bs[k] * 256 + lane;
              g0[k] = row[0]; g1[k] = row[64]; g2[k] = row[128]; g3[k] = row[192];
            } else { g0[k] = 0.0; g1[k] = 0.0; g2[k] = 0.0; g3[k] = 0.0; }
          }
#pragma unroll
          for (int k = 0; k < 4; ++k) {           // ascending member order kept
            a0 += g0[k]; a1 += g1[k]; a2 += g2[k]; a3 += g3[k];
          }
        }
      }
      S[j][lane] = a0; S[j][64 + lane] = a1; S[j][128 + lane] = a2; S[j][192 + lane] = a3;
    }
    __syncthreads();                             // B4

    // ---- P4: Q for dirty clusters (serial ascending LDS sum, 4-wide loads) ----
    if (tid < KC) {
      if (dirty[tid]) {
        int c = cnt[tid];
        double q = 0.0;
#pragma unroll
        for (int w = 0; w < 4; ++w) {
          unsigned long long mm = membwN[tid][w];
          while (mm) {
            double sv[4];
#pragma unroll
            for (int k = 0; k < 4; ++k) sv[k] = 0.0;
#pragma unroll
            for (int k = 0; k < 4; ++k) {
              if (mm) { int b = __builtin_ctzll(mm); mm &= mm - 1; sv[k] = S[tid][w * 64 + b]; }
            }
#pragma unroll
            for (int k = 0; k < 4; ++k) q += sv[k];
          }
        }
        double n = (double)c;
        Ns[tid] = c;
        qi[tid][1] = 1.0 / n;
        qi[tid][0] = q / (n * n);
      }
    }
    __syncthreads();                             // B5
  }

  // ---- final assignment (same split + merge) ----
  {
    double bd = 1e300; int bj = 0;
#pragma unroll
    for (int t = 0; t < 15; ++t) {
      int j = z * 15 + t;
      double2 qv = *(const double2*)&qi[j][0];
      double dd = gii + qv.x - 2.0 * S[j][i] * qv.y;
      if (dd < bd) { bd = dd; bj = j; }
    }
    pminD[z][i] = bd; pminJ[z][i] = bj;
  }
  if (tid < 64) { counts64[tid] = 0; tsum64[tid] = 0; }
  __syncthreads();
  if (z == 0) {
    double bd = pminD[0][i]; int bb = pminJ[0][i];
#pragma unroll
    for (int g = 1; g < 4; ++g) {
      double d2 = pminD[g][i];
      if (d2 < bd) { bd = d2; bb = pminJ[g][i]; }
    }
    atomicAdd(&counts64[bb], 1);
    atomicAdd(&tsum64[bb], i);
  }
  __syncthreads();
  if (tid < KC) times[tid] = (float)tsum64[tid] / fmaxf((float)counts64[tid], 1.0f);
  __syncthreads();
  if (tid < KC) {                                // stable argsort(times)
    float ti = times[tid]; int r = 0;
    for (int s = 0; s < KC; ++s) {
      float ts = times[s];
      r += (ts < ti) || (ts == ti && s < tid);
    }
    ord[r] = tid;
  }
  __syncthreads();
  if (tid < KC) wts[tid] = (float)counts64[ord[tid]];
  __syncthreads();
  if (tid < KC) {                                // stable argsort(-wts)
    float wi = wts[tid]; int r = 0;
    for (int s = 0; s < KC; ++s) {
      float wsv = wts[s];
      r += (wsv > wi) || (wsv == wi && s < tid);
    }
    ord2[r] = tid;
  }
  __syncthreads();
  if (tid < KC) {
    int j = ord[tid];
    orderws[tid] = j;
    out_w[tid] = (float)counts64[j];
    out_ts[tid] = rintf(times[j]);
    Nout[tid] = Ns[tid];
  }
  if (tid < NSEL) sel[tid] = ord[ord2[tid]];
  if (tid < KC) {                                // member lists (last-live membership)
    int c = 0;
#pragma unroll
    for (int w = 0; w < 4; ++w) {
      unsigned long long mm = membw[tid][w];
      while (mm) {
        int b = __builtin_ctzll(mm);
        mlist[tid * 256 + (c++)] = w * 64 + b;
        mm &= mm - 1;
      }
    }
    mcount[tid] = c;
  }
  __syncthreads();

  // ---- distidx: 30 argmins; wave w handles sels {w, w+16} ----
  {
    for (int s = wid; s < NSEL; s += 16) {
      int j = sel[s];
      double qn = qi[j][0], iv = qi[j][1];
      unsigned long long key = ~0ULL;
#pragma unroll
      for (int q = 0; q < 4; ++q) {
        int p = lane + 64 * q;
        double v = giiL[p] + qn - 2.0 * S[j][p] * iv;
        float dd = sqrtf(fmaxf((float)v, 0.0f));
        unsigned long long k = (((unsigned long long)__float_as_uint(dd)) << 32) | (unsigned)p;
        if (k < key) key = k;
      }
#pragma unroll
      for (int o = 32; o > 0; o >>= 1) {
        unsigned long long other = __shfl_xor(key, o, 64);
        if (other < key) key = other;
      }
      if (lane == 0) { int bi = (int)(key & 0xffffffffULL); idxws[s] = bi; out_idx[s] = (float)bi; }
    }
  }
}

// ---------------- Stage E fused: gather_spa + write_tem ---------------------
__global__ void tail_kernel(const float* __restrict__ x, const int* __restrict__ idxws,
                            const __hip_bfloat16* __restrict__ HB,
                            const __hip_bfloat16* __restrict__ MB,
                            const int* __restrict__ orderws,
                            const int* __restrict__ mcount, const int* __restrict__ mlist,
                            const int* __restrict__ N,
                            float* __restrict__ out_cat, float* __restrict__ out_tem) {
  int bid = blockIdx.x;
  if (bid < 8820) {
    int pos = bid * 256 + threadIdx.x;           // 30*75264 float4s
    int s = pos / 75264;
    int o = pos - s * 75264;
    ((float4*)out_cat)[pos] = ((const float4*)x)[(size_t)idxws[s] * 75264 + o];
  } else {
    int b2 = bid - 8820;
    int r = b2 / 37, g = b2 - r * 37;
    int col8 = g * 256 + threadIdx.x;            // 9408 groups of 8 elements
    if (col8 >= 9408) return;
    int j = orderws[r];
    int cntm = mcount[j];
    float n = (float)N[j];
    float acc[8];
#pragma unroll
    for (int k = 0; k < 8; ++k) acc[k] = 0.f;
    for (int m = 0; m < cntm; ++m) {
      int p = mlist[j * 256 + m];
      u16x8 hv = *(const u16x8*)((const unsigned short*)HB + (size_t)p * GK + (size_t)col8 * 8);
      u16x8 mv = *(const u16x8*)((const unsigned short*)MB + (size_t)p * GK + (size_t)col8 * 8);
#pragma unroll
      for (int k = 0; k < 8; ++k) acc[k] += b2f(hv[k]) + b2f(mv[k]);
    }
    float4 o0 = make_float4(acc[0] / n, acc[1] / n, acc[2] / n, acc[3] / n);
    float4 o1 = make_float4(acc[4] / n, acc[5] / n, acc[6] / n, acc[7] / n);
    float4* dst = (float4*)out_tem + (size_t)r * 18816 + (size_t)col8 * 2;
    dst[0] = o0;
    dst[1] = o1;
  }
}

extern "C" void kernel_launch(void* const* d_in, const int* in_sizes, int n_in,
                              void* d_out, int out_size, void* d_ws, size_t ws_size,
                              hipStream_t stream) {
  const float* x = (const float*)d_in[0];
  char* ws = (char*)d_ws;
  size_t off = 0;
  __hip_bfloat16* HB = (__hip_bfloat16*)(ws + off); off += (size_t)19267584 * 2;  // 38.5 MB
  __hip_bfloat16* MB = (__hip_bfloat16*)(ws + off); off += (size_t)19267584 * 2;  // 38.5 MB
  double* G    = (double*)(ws + off);    off += (size_t)65536 * 8;
  int* orderws = (int*)(ws + off);       off += 256;
  int* idxws   = (int*)(ws + off);       off += 256;
  int* mcount  = (int*)(ws + off);       off += 256;
  int* Nws     = (int*)(ws + off);       off += 256;
  int* mlist   = (int*)(ws + off);       off += (size_t)KC * 256 * 4;

  float* out = (float*)d_out;
  float* gpart = out;  // NCH*256KB = 51.4 MB scratch inside cat_x region; overwritten later

  const size_t o_cat = 0;
  const size_t o_tem = 9031680;
  const size_t o_idx = 13547520;
  const size_t o_ts  = o_idx + 30;
  const size_t o_w   = o_ts + 60;

  pool_kernel<<<75264, 256, 0, stream>>>(x, HB, MB);
  gram_mfma<<<NCH, 512, 0, stream>>>((const unsigned short*)HB, (const unsigned short*)MB, gpart);
  reduceG<<<256, 256, 0, stream>>>(gpart, G);
  kmeans_all<<<1, 1024, 0, stream>>>(G, orderws, idxws, mcount, mlist, Nws,
                                     out + o_idx, out + o_ts, out + o_w);
  tail_kernel<<<8820 + KC * 37, 256, 0, stream>>>(x, idxws, HB, MB, orderws, mcount, mlist,
                                                  Nws, out + o_cat, out + o_tem);
}